// Round 1
// baseline (98.278 us; speedup 1.0000x reference)
//
#include <hip/hip_runtime.h>

#define K 12
#define NKB 4
#define PIECE_DIM (K * 64)       // 768
#define NROWS (NKB * PIECE_DIM)  // 3072
#define DOUT 128
#define BATCH 16384
#define SEQL 32

// ---------------------------------------------------------------------------
// Kernel 1: build the merged weight table
//   w[nkb,k,r,f,d] = tiles + (pieces + ranks + files)*fmask + noking
// Shape (NKB, K, 8, 8, DOUT) flattened to (3072, 128).
// ---------------------------------------------------------------------------
__global__ __launch_bounds__(DOUT) void build_w_kernel(
    const float* __restrict__ pieces,   // (NKB,K,1,1,DOUT)
    const float* __restrict__ ranks,    // (NKB,K,8,1,DOUT)
    const float* __restrict__ files,    // (NKB,K,1,8,DOUT)
    const float* __restrict__ noking,   // (1,K,8,8,DOUT)
    const float* __restrict__ tiles,    // (NKB,K,8,8,DOUT)
    const float* __restrict__ fmask,    // (NKB,K,8,8,1)
    float* __restrict__ w)              // (NROWS, DOUT)
{
    int row = blockIdx.x;               // 0..3071
    int d   = threadIdx.x;              // 0..127
    int nkb = row / PIECE_DIM;
    int rem = row - nkb * PIECE_DIM;    // 0..767
    int k   = rem >> 6;
    int sq  = rem & 63;
    int r   = sq >> 3;
    int f   = sq & 7;
    int nk_k = nkb * K + k;

    float p  = pieces[nk_k * DOUT + d];
    float rk = ranks[(nk_k * 8 + r) * DOUT + d];
    float fl = files[(nk_k * 8 + f) * DOUT + d];
    float nk = noking[((k * 8 + r) * 8 + f) * DOUT + d];
    float tl = tiles[((nk_k * 8 + r) * 8 + f) * DOUT + d];
    float fm = fmask[(nk_k * 8 + r) * 8 + f];

    w[row * DOUT + d] = tl + (p + rk + fl) * fm + nk;
}

// ---------------------------------------------------------------------------
// KING_BUCKETS: only indices 56,57 -> 3, 60 -> 1, 62,63 -> 2 are nonzero.
// Packed as 2-bit fields in one u64 covering indices 32..63.
// ---------------------------------------------------------------------------
__device__ __forceinline__ int king_bucket(int s) {
    const unsigned long long hi =
        (3ULL << 48) | (3ULL << 50) | (1ULL << 56) | (2ULL << 60) | (2ULL << 62);
    int t = s - 32;
    return (t >= 0) ? (int)((hi >> (2 * t)) & 3ULL) : 0;
}

// ---------------------------------------------------------------------------
// Kernel 2: one wave per batch. Lanes 0-31: mover slice, lanes 32-63: waiter.
// Each lane accumulates one float4 (4 of the 128 channels) over 32 tokens.
// ---------------------------------------------------------------------------
__global__ __launch_bounds__(256) void gather_kernel(
    const int* __restrict__ values,   // (BATCH*SEQL)
    const int* __restrict__ kings,    // (BATCH,2)
    const float* __restrict__ w,      // (NROWS, DOUT)
    float* __restrict__ out)          // a:(BATCH,DOUT) then b:(BATCH,DOUT)
{
    int wave = threadIdx.x >> 6;
    int lane = threadIdx.x & 63;
    int b    = blockIdx.x * 4 + wave;
    int half = lane >> 5;             // 0 = mover, 1 = waiter
    int c    = lane & 31;             // float4 index within the row

    int km   = kings[2 * b];
    int kw   = kings[2 * b + 1];
    int mbkt = king_bucket(km);
    int wbkt = king_bucket(kw ^ 56);  // vertical flip of waiter king square
    int base = (half ? wbkt : mbkt) * PIECE_DIM;

    const float4* wp = (const float4*)w;            // row stride = 32 float4
    const int4*   vp = (const int4*)(values + b * SEQL);

    float4 acc = make_float4(0.f, 0.f, 0.f, 0.f);

    #pragma unroll
    for (int j = 0; j < SEQL / 4; ++j) {
        int4 vv = vp[j];              // wave-uniform address -> broadcast
        int vs[4] = {vv.x, vv.y, vv.z, vv.w};
        #pragma unroll
        for (int u = 0; u < 4; ++u) {
            int v     = vs[u];
            int sq    = v & 63;
            int piece = v >> 6;
            int p2    = piece + ((piece < 6) ? 6 : -6);   // (piece+6)%12
            int wv    = (p2 << 6) | (sq ^ 56);            // flipped value
            int rv    = half ? wv : v;
            float4 x  = wp[(base + rv) * (DOUT / 4) + c];
            acc.x += x.x; acc.y += x.y; acc.z += x.z; acc.w += x.w;
        }
    }

    acc.x = fminf(fmaxf(acc.x, 0.f), 1.f);
    acc.y = fminf(fmaxf(acc.y, 0.f), 1.f);
    acc.z = fminf(fmaxf(acc.z, 0.f), 1.f);
    acc.w = fminf(fmaxf(acc.w, 0.f), 1.f);

    float4* dst = (float4*)(out + (size_t)half * (BATCH * DOUT) + (size_t)b * DOUT) + c;
    *dst = acc;
}

extern "C" void kernel_launch(void* const* d_in, const int* in_sizes, int n_in,
                              void* d_out, int out_size, void* d_ws, size_t ws_size,
                              hipStream_t stream) {
    const int*   values = (const int*)d_in[0];
    // d_in[1] = lengths: uniformly SEQL with BATCH*SEQL == T, so segment b
    // owns tokens [SEQL*b, SEQL*(b+1)) — start offsets computed directly.
    const int*   kings  = (const int*)d_in[2];
    const float* pieces = (const float*)d_in[3];
    const float* ranks  = (const float*)d_in[4];
    const float* files  = (const float*)d_in[5];
    const float* noking = (const float*)d_in[6];
    const float* tiles  = (const float*)d_in[7];
    const float* fmask  = (const float*)d_in[8];

    float* w   = (float*)d_ws;   // needs NROWS*DOUT*4 = 1.5 MB of scratch
    float* out = (float*)d_out;

    build_w_kernel<<<NROWS, DOUT, 0, stream>>>(pieces, ranks, files, noking,
                                               tiles, fmask, w);
    gather_kernel<<<BATCH / 4, 256, 0, stream>>>(values, kings, w, out);
}